// Round 13
// baseline (75.410 us; speedup 1.0000x reference)
//
#include <hip/hip_runtime.h>
#include <float.h>
#include <stdint.h>

#define N_TOKENS 65536
#define N_EMB    1024
#define DIM      256

typedef __attribute__((ext_vector_type(4))) int int4v;

// async global->LDS, 16B per lane (dest = wave-uniform base + lane*16)
__device__ __forceinline__ void gld_lds16(const void* g, void* l) {
    __builtin_amdgcn_global_load_lds(
        (__attribute__((address_space(1))) void*)(g),
        (__attribute__((address_space(3))) void*)(l), 16, 0, 0);
}

// ---------------- kernel 1: fused prep = norms (f32 + x2^20 int) + i8(x2^17) image ----------
// (UNCHANGED from rounds 11/12 — identical cn2/cnI/img bytes.)
__global__ __launch_bounds__(256) void prep_kernel(const float* __restrict__ cb,
                                                   float* __restrict__ cn2,
                                                   int* __restrict__ cnI,
                                                   unsigned char* __restrict__ img) {
    const int t = threadIdx.x, w = t >> 6, lane = t & 63;
#pragma unroll
    for (int u = 0; u < 2; ++u) {
        const int c = blockIdx.x * 8 + w * 2 + u;
        float4 v = ((const float4*)cb)[c * 64 + lane];
        float s = v.x * v.x + v.y * v.y + v.z * v.z + v.w * v.w;
#pragma unroll
        for (int m = 1; m < 64; m <<= 1) s += __shfl_xor(s, m);
        if (lane == 0) { cn2[c] = s; cnI[c] = (int)rintf(s * 1048576.f); }
        int a0 = (int)fminf(fmaxf(rintf(v.x * 131072.f), -127.f), 127.f);
        int a1 = (int)fminf(fmaxf(rintf(v.y * 131072.f), -127.f), 127.f);
        int a2 = (int)fminf(fmaxf(rintf(v.z * 131072.f), -127.f), 127.f);
        int a3 = (int)fminf(fmaxf(rintf(v.w * 131072.f), -127.f), 127.f);
        unsigned pw = (a0 & 255) | ((a1 & 255) << 8) | ((a2 & 255) << 16) | ((a3 & 255) << 24);
        int src = (lane >> 2) * 16 + (lane & 3) * 4;
        unsigned u0 = (unsigned)__shfl((int)pw, src + 0);
        unsigned u1 = (unsigned)__shfl((int)pw, src + 1);
        unsigned u2 = (unsigned)__shfl((int)pw, src + 2);
        unsigned u3 = (unsigned)__shfl((int)pw, src + 3);
        if (lane < 16) {
            int ks = lane >> 2, g = lane & 3;
            int T = c >> 5, half = (c >> 4) & 1;
            int gid = T * 512 + (ks * 2 + half) * 64 + g * 16 + (c & 15);
            uint4 o; o.x = u0; o.y = u1; o.z = u2; o.w = u3;
            ((uint4*)img)[gid] = o;
        }
    }
}

// ---------------- kernel 2: fused VQ — single-wave blocks, ZERO barriers, i8 MFMA -----------
// 2048 blocks x 64 thr, 32 tokens/wave (r11 per-wave economics). B tiles staged by
// global_load_lds into 3 rotating 8KB buffers, counted vmcnt(8) — never a drain, never
// a barrier. 5 resident blocks/CU of 8 assigned -> queued blocks overlap their A-load /
// out-write with residents' K-loops (phase diversity without lockstep).
__global__ __launch_bounds__(64, 2) void fused_vq_kernel(
        const float* __restrict__ z, const unsigned char* __restrict__ cbimg,
        const float* __restrict__ cb, const float* __restrict__ cn2,
        const int* __restrict__ cnI,
        float* __restrict__ out, float* __restrict__ partials) {
    __shared__ char  Bs[3][8192];                 // 3 x 8KB B tiles
    __shared__ int   cnIS[N_EMB];                 // 4KB int keys
    __shared__ int   winS[32];
    __shared__ float distS[32];
    __shared__ float xnS[32];
    const int lane = threadIdx.x;                 // 0..63
    const int col = lane & 15, g = lane >> 4;

    const char* srcL = (const char*)cbimg + lane * 16;

    // prologue: issue tiles 0 and 1 (8 gld_lds each; wave stages the whole tile)
#pragma unroll
    for (int j = 0; j < 8; ++j) gld_lds16(srcL + j * 1024, &Bs[0][0] + j * 1024);
#pragma unroll
    for (int j = 0; j < 8; ++j) gld_lds16(srcL + 8192 + j * 1024, &Bs[1][0] + j * 1024);

    // cnI table -> LDS (in-wave ds ordering; no barrier needed anywhere)
#pragma unroll
    for (int i = 0; i < 16; ++i) cnIS[lane + i * 64] = cnI[lane + i * 64];

    // A: 32 tokens as i8(16*z) (truncating cvt, r11-verbatim); xn exact fp32
    int4v ah[2][4];
    float xnp[2] = {0.f, 0.f};
    const int rbase = blockIdx.x * 32 + col;
#pragma unroll
    for (int m = 0; m < 2; ++m) {
#pragma unroll
        for (int ks = 0; ks < 4; ++ks) {
            const float* p = z + (size_t)(rbase + m * 16) * DIM + ks * 64 + g * 16;
            float4 x0 = *(const float4*)p;
            float4 x1 = *(const float4*)(p + 4);
            float4 x2 = *(const float4*)(p + 8);
            float4 x3 = *(const float4*)(p + 12);
            xnp[m] = fmaf(x0.x, x0.x, xnp[m]); xnp[m] = fmaf(x0.y, x0.y, xnp[m]);
            xnp[m] = fmaf(x0.z, x0.z, xnp[m]); xnp[m] = fmaf(x0.w, x0.w, xnp[m]);
            xnp[m] = fmaf(x1.x, x1.x, xnp[m]); xnp[m] = fmaf(x1.y, x1.y, xnp[m]);
            xnp[m] = fmaf(x1.z, x1.z, xnp[m]); xnp[m] = fmaf(x1.w, x1.w, xnp[m]);
            xnp[m] = fmaf(x2.x, x2.x, xnp[m]); xnp[m] = fmaf(x2.y, x2.y, xnp[m]);
            xnp[m] = fmaf(x2.z, x2.z, xnp[m]); xnp[m] = fmaf(x2.w, x2.w, xnp[m]);
            xnp[m] = fmaf(x3.x, x3.x, xnp[m]); xnp[m] = fmaf(x3.y, x3.y, xnp[m]);
            xnp[m] = fmaf(x3.z, x3.z, xnp[m]); xnp[m] = fmaf(x3.w, x3.w, xnp[m]);
            int4v fr;
#pragma unroll
            for (int q = 0; q < 4; ++q) {
                const float4& xq = q == 0 ? x0 : (q == 1 ? x1 : (q == 2 ? x2 : x3));
                int b0 = (int)(xq.x * 16.f), b1 = (int)(xq.y * 16.f);
                int b2 = (int)(xq.z * 16.f), b3 = (int)(xq.w * 16.f);
                fr[q] = (b0 & 255) | ((b1 & 255) << 8) | ((b2 & 255) << 16) | ((b3 & 255) << 24);
            }
            ah[m][ks] = fr;
        }
    }
    xnp[0] += __shfl_xor(xnp[0], 16); xnp[0] += __shfl_xor(xnp[0], 32);
    xnp[1] += __shfl_xor(xnp[1], 16); xnp[1] += __shfl_xor(xnp[1], 32);
    if (g == 0) { xnS[col] = xnp[0]; xnS[16 + col] = xnp[1]; }

    int best[2][4], bidx[2][4];
#pragma unroll
    for (int m = 0; m < 2; ++m)
#pragma unroll
        for (int r = 0; r < 4; ++r) { best[m][r] = INT32_MIN; bidx[m][r] = 0; }

    const char* rd0 = &Bs[0][0];
    const char* rd1 = &Bs[1][0];
    const char* rd2 = &Bs[2][0];

    for (int T = 0; T < 32; ++T) {
        // tile T resident when the 8 loads older than tile T+1's are done
        if (T < 31) asm volatile("s_waitcnt vmcnt(8)" ::: "memory");
        else        asm volatile("s_waitcnt vmcnt(0)" ::: "memory");
        __builtin_amdgcn_sched_barrier(0);
        if (T + 2 < 32) {                         // issue tile T+2 into buffer read at T-1
            const char* s2 = srcL + (T + 2) * 8192;
            char* wq2 = (char*)rd2;
#pragma unroll
            for (int j = 0; j < 8; ++j) gld_lds16(s2 + j * 1024, wq2 + j * 1024);
        }
        const int code0 = T * 32 + col;
        const int code1 = code0 + 16;
        const int c0I = cnIS[code0], c1I = cnIS[code1];
        int4v a00 = {-c0I, -c0I, -c0I, -c0I};
        int4v a01 = {-c1I, -c1I, -c1I, -c1I};
        int4v a10 = a00, a11 = a01;
        __builtin_amdgcn_s_setprio(1);
#pragma unroll
        for (int ks = 0; ks < 4; ++ks) {
            int4v b0 = *(const int4v*)(rd0 + (ks * 2 + 0) * 1024 + (lane << 4));
            int4v b1 = *(const int4v*)(rd0 + (ks * 2 + 1) * 1024 + (lane << 4));
            a00 = __builtin_amdgcn_mfma_i32_16x16x64_i8(ah[0][ks], b0, a00, 0, 0, 0);
            a10 = __builtin_amdgcn_mfma_i32_16x16x64_i8(ah[1][ks], b0, a10, 0, 0, 0);
            a01 = __builtin_amdgcn_mfma_i32_16x16x64_i8(ah[0][ks], b1, a01, 0, 0, 0);
            a11 = __builtin_amdgcn_mfma_i32_16x16x64_i8(ah[1][ks], b1, a11, 0, 0, 0);
        }
        __builtin_amdgcn_s_setprio(0);
        // integer argmin: maximize accI' = 2^21*dot - cnI (codes ascending -> first-min ties)
#pragma unroll
        for (int r = 0; r < 4; ++r) {
            if (a00[r] > best[0][r]) { best[0][r] = a00[r]; bidx[0][r] = code0; }
            if (a01[r] > best[0][r]) { best[0][r] = a01[r]; bidx[0][r] = code1; }
            if (a10[r] > best[1][r]) { best[1][r] = a10[r]; bidx[1][r] = code0; }
            if (a11[r] > best[1][r]) { best[1][r] = a11[r]; bidx[1][r] = code1; }
        }
        const char* tr = rd0; rd0 = rd1; rd1 = rd2; rd2 = tr;
    }

    // in-wave merge across 16 col-lanes; token = m*16 + g*4 + r   (r11-verbatim logic)
#pragma unroll
    for (int m = 0; m < 2; ++m)
#pragma unroll
        for (int r = 0; r < 4; ++r) {
            int a  = best[m][r];
            int cd = bidx[m][r];
#pragma unroll
            for (int mask = 1; mask <= 8; mask <<= 1) {
                int oa = __shfl_xor(a, mask);
                int oc = __shfl_xor(cd, mask);
                if (oa > a || (oa == a && oc < cd)) { a = oa; cd = oc; }
            }
            if (col == 0) {
                int tl = m * 16 + g * 4 + r;
                winS[tl] = cd;
                // score = cn - 2*dot = cn - (accI' + cnI)*2^-20
                distS[tl] = fmaf((float)(a + cnIS[cd]), -9.5367431640625e-07f, cn2[cd]);
            }
        }
    // single wave: in-order DS + compiler lgkmcnt make winS/distS/xnS readable; no barrier.

    // loss partial: sum over the block's 32 tokens of (xn + score_win)
    {
        float s = (lane < 32) ? (xnS[lane] + distS[lane]) : 0.f;
#pragma unroll
        for (int m = 1; m < 64; m <<= 1) s += __shfl_xor(s, m);
        if (lane == 0) partials[blockIdx.x] = s;
    }

    // out-write: 32 tokens x 1KB; winner row coalesced from L2-hot cb
    const size_t ob = (size_t)blockIdx.x * 2048;  // float4 units
#pragma unroll 4
    for (int i = 0; i < 32; ++i) {
        int k = winS[i];                          // wave-uniform
        float4 qv = ((const float4*)cb)[k * 64 + lane];
        ((float4*)out)[ob + i * 64 + lane] = qv;
    }
}

// ---------------- kernel 3: deterministic partial reduction (2048 partials) ----------------
__global__ __launch_bounds__(256) void reduce_kernel(const float* __restrict__ partials,
                                                     float* __restrict__ out_loss) {
    const int tid = threadIdx.x;
    float s = 0.f;
#pragma unroll
    for (int u = 0; u < 8; ++u) s += partials[tid + 256 * u];
#pragma unroll
    for (int m = 1; m < 64; m <<= 1) s += __shfl_xor(s, m);
    __shared__ float wsum[4];
    if ((tid & 63) == 0) wsum[tid >> 6] = s;
    __syncthreads();
    if (tid == 0) *out_loss = 2.0f * ((wsum[0] + wsum[1]) + (wsum[2] + wsum[3]));
}

extern "C" void kernel_launch(void* const* d_in, const int* in_sizes, int n_in,
                              void* d_out, int out_size, void* d_ws, size_t ws_size,
                              hipStream_t stream) {
    const float* z  = (const float*)d_in[0];   // z_e       [65536,256]
    const float* cb = (const float*)d_in[1];   // codebook  [1024,256]
    float* out = (float*)d_out;
    char*  ws  = (char*)d_ws;

    float*         cn2      = (float*)(ws);                    // 4 KB
    int*           cnI      = (int*)(ws + 4096);               // 4 KB
    float*         partials = (float*)(ws + 8192);             // 8 KB
    unsigned char* cbimg    = (unsigned char*)(ws + 16384);    // 256 KB

    prep_kernel    <<<128, 256, 0, stream>>>(cb, cn2, cnI, cbimg);
    fused_vq_kernel<<<2048, 64, 0, stream>>>(z, cbimg, cb, cn2, cnI, out, partials);
    reduce_kernel  <<<1, 256, 0, stream>>>(partials, out + (size_t)N_TOKENS * DIM);
}

// Round 14
// 49.406 us; speedup vs baseline: 1.5263x; 1.5263x over previous
//
#include <hip/hip_runtime.h>
#include <float.h>
#include <stdint.h>

#define N_TOKENS 65536
#define N_EMB    1024
#define DIM      256

typedef __attribute__((ext_vector_type(4))) int int4v;

// async global->LDS, 16B per lane (dest = wave-uniform base + lane*16)
__device__ __forceinline__ void gld_lds16(const void* g, void* l) {
    __builtin_amdgcn_global_load_lds(
        (__attribute__((address_space(1))) void*)(g),
        (__attribute__((address_space(3))) void*)(l), 16, 0, 0);
}

// ---------------- kernel 1: fused prep = norms (f32 + x2^20 int) + i8(x2^17) image ----------
// (UNCHANGED from round 11 — identical cn2/cnI/img bytes.)
__global__ __launch_bounds__(256) void prep_kernel(const float* __restrict__ cb,
                                                   float* __restrict__ cn2,
                                                   int* __restrict__ cnI,
                                                   unsigned char* __restrict__ img) {
    const int t = threadIdx.x, w = t >> 6, lane = t & 63;
#pragma unroll
    for (int u = 0; u < 2; ++u) {
        const int c = blockIdx.x * 8 + w * 2 + u;
        float4 v = ((const float4*)cb)[c * 64 + lane];
        float s = v.x * v.x + v.y * v.y + v.z * v.z + v.w * v.w;
#pragma unroll
        for (int m = 1; m < 64; m <<= 1) s += __shfl_xor(s, m);
        if (lane == 0) { cn2[c] = s; cnI[c] = (int)rintf(s * 1048576.f); }
        int a0 = (int)fminf(fmaxf(rintf(v.x * 131072.f), -127.f), 127.f);
        int a1 = (int)fminf(fmaxf(rintf(v.y * 131072.f), -127.f), 127.f);
        int a2 = (int)fminf(fmaxf(rintf(v.z * 131072.f), -127.f), 127.f);
        int a3 = (int)fminf(fmaxf(rintf(v.w * 131072.f), -127.f), 127.f);
        unsigned pw = (a0 & 255) | ((a1 & 255) << 8) | ((a2 & 255) << 16) | ((a3 & 255) << 24);
        int src = (lane >> 2) * 16 + (lane & 3) * 4;
        unsigned u0 = (unsigned)__shfl((int)pw, src + 0);
        unsigned u1 = (unsigned)__shfl((int)pw, src + 1);
        unsigned u2 = (unsigned)__shfl((int)pw, src + 2);
        unsigned u3 = (unsigned)__shfl((int)pw, src + 3);
        if (lane < 16) {
            int ks = lane >> 2, g = lane & 3;
            int T = c >> 5, half = (c >> 4) & 1;
            int gid = T * 512 + (ks * 2 + half) * 64 + g * 16 + (c & 15);
            uint4 o; o.x = u0; o.y = u1; o.z = u2; o.w = u3;
            ((uint4*)img)[gid] = o;
        }
    }
}

// ---------------- kernel 2: fused VQ — r11 chassis + double-tile K-steps (16 barriers) ------
// 512 blocks x 256 thr (4 waves), 32 tokens/wave. B staged as 16KB double-tiles (64 codes)
// into 3 rotating buffers via global_load_lds (4 loads/wave/buffer), counted vmcnt(4),
// ONE barrier per double-tile. Quantization/argmin/score arithmetic r11-verbatim.
__global__ __launch_bounds__(256, 2) void fused_vq_kernel(
        const float* __restrict__ z, const unsigned char* __restrict__ cbimg,
        const float* __restrict__ cb, const float* __restrict__ cn2,
        const int* __restrict__ cnI,
        float* __restrict__ out, float* __restrict__ partials) {
    __shared__ char  Bs[3][16384];                // 3 x 16KB double-tiles
    __shared__ float cnS[N_EMB];                  // 4KB float norms
    __shared__ int   cnIS[N_EMB];                 // 4KB int keys
    __shared__ int   winS[128];
    __shared__ float distS[128];
    __shared__ float xnS[128];
    const int t = threadIdx.x;
    const int lane = t & 63, w = t >> 6;
    const int col = lane & 15, g = lane >> 4;

    const char* srcL = (const char*)cbimg + w * 4096 + lane * 16;  // wave quarter (4KB)
    char* q0 = &Bs[0][0] + w * 4096;
    char* q1 = &Bs[1][0] + w * 4096;
    char* q2 = &Bs[2][0] + w * 4096;

    // prologue: issue double-tiles 0 and 1 (4 gld_lds per wave each)
#pragma unroll
    for (int j = 0; j < 4; ++j) gld_lds16(srcL + j * 1024, q0 + j * 1024);
#pragma unroll
    for (int j = 0; j < 4; ++j) gld_lds16(srcL + 16384 + j * 1024, q1 + j * 1024);

    // A: 32 tokens/wave as i8(16*z) (truncating cvt); xn exact fp32  (r11-verbatim)
    int4v ah[2][4];
    float xnp[2] = {0.f, 0.f};
    const int rbase = blockIdx.x * 128 + w * 32 + col;
#pragma unroll
    for (int m = 0; m < 2; ++m) {
#pragma unroll
        for (int ks = 0; ks < 4; ++ks) {
            const float* p = z + (size_t)(rbase + m * 16) * DIM + ks * 64 + g * 16;
            float4 x0 = *(const float4*)p;
            float4 x1 = *(const float4*)(p + 4);
            float4 x2 = *(const float4*)(p + 8);
            float4 x3 = *(const float4*)(p + 12);
            xnp[m] = fmaf(x0.x, x0.x, xnp[m]); xnp[m] = fmaf(x0.y, x0.y, xnp[m]);
            xnp[m] = fmaf(x0.z, x0.z, xnp[m]); xnp[m] = fmaf(x0.w, x0.w, xnp[m]);
            xnp[m] = fmaf(x1.x, x1.x, xnp[m]); xnp[m] = fmaf(x1.y, x1.y, xnp[m]);
            xnp[m] = fmaf(x1.z, x1.z, xnp[m]); xnp[m] = fmaf(x1.w, x1.w, xnp[m]);
            xnp[m] = fmaf(x2.x, x2.x, xnp[m]); xnp[m] = fmaf(x2.y, x2.y, xnp[m]);
            xnp[m] = fmaf(x2.z, x2.z, xnp[m]); xnp[m] = fmaf(x2.w, x2.w, xnp[m]);
            xnp[m] = fmaf(x3.x, x3.x, xnp[m]); xnp[m] = fmaf(x3.y, x3.y, xnp[m]);
            xnp[m] = fmaf(x3.z, x3.z, xnp[m]); xnp[m] = fmaf(x3.w, x3.w, xnp[m]);
            int4v fr;
#pragma unroll
            for (int q = 0; q < 4; ++q) {
                const float4& xq = q == 0 ? x0 : (q == 1 ? x1 : (q == 2 ? x2 : x3));
                int b0 = (int)(xq.x * 16.f), b1 = (int)(xq.y * 16.f);
                int b2 = (int)(xq.z * 16.f), b3 = (int)(xq.w * 16.f);
                fr[q] = (b0 & 255) | ((b1 & 255) << 8) | ((b2 & 255) << 16) | ((b3 & 255) << 24);
            }
            ah[m][ks] = fr;
        }
    }
    xnp[0] += __shfl_xor(xnp[0], 16); xnp[0] += __shfl_xor(xnp[0], 32);
    xnp[1] += __shfl_xor(xnp[1], 16); xnp[1] += __shfl_xor(xnp[1], 32);
    if (g == 0) { xnS[w * 32 + col] = xnp[0]; xnS[w * 32 + 16 + col] = xnp[1]; }
#pragma unroll
    for (int i = 0; i < 4; ++i) {
        cnS[t + i * 256]  = cn2[t + i * 256];
        cnIS[t + i * 256] = cnI[t + i * 256];
    }

    int best[2][4], bidx[2][4];
#pragma unroll
    for (int m = 0; m < 2; ++m)
#pragma unroll
        for (int r = 0; r < 4; ++r) { best[m][r] = INT32_MIN; bidx[m][r] = 0; }

    asm volatile("s_waitcnt lgkmcnt(0)" ::: "memory");  // cnS/cnIS/xnS visible

    const char* rd0 = &Bs[0][0];
    const char* rd1 = &Bs[1][0];
    const char* rd2 = &Bs[2][0];
    char *wq0 = q0, *wq1 = q1, *wq2 = q2;

    for (int P = 0; P < 16; ++P) {                // P = double-tile (64 codes)
        if (P < 15) asm volatile("s_waitcnt vmcnt(4)" ::: "memory");
        else        asm volatile("s_waitcnt vmcnt(0)" ::: "memory");
        __builtin_amdgcn_s_barrier();             // all waves: double-tile P resident
        __builtin_amdgcn_sched_barrier(0);
        if (P + 2 < 16) {                         // issue double-tile P+2
            const char* s2 = srcL + (P + 2) * 16384;
#pragma unroll
            for (int j = 0; j < 4; ++j) gld_lds16(s2 + j * 1024, wq2 + j * 1024);
        }
#pragma unroll
        for (int h = 0; h < 2; ++h) {             // two 32-code sub-tiles
            const char* sub = rd0 + h * 8192;
            const int T = P * 2 + h;
            const int code0 = T * 32 + col;
            const int code1 = code0 + 16;
            const int c0I = cnIS[code0], c1I = cnIS[code1];
            int4v a00 = {-c0I, -c0I, -c0I, -c0I};
            int4v a01 = {-c1I, -c1I, -c1I, -c1I};
            int4v a10 = a00, a11 = a01;
            __builtin_amdgcn_s_setprio(1);
#pragma unroll
            for (int ks = 0; ks < 4; ++ks) {
                int4v b0 = *(const int4v*)(sub + (ks * 2 + 0) * 1024 + (lane << 4));
                int4v b1 = *(const int4v*)(sub + (ks * 2 + 1) * 1024 + (lane << 4));
                a00 = __builtin_amdgcn_mfma_i32_16x16x64_i8(ah[0][ks], b0, a00, 0, 0, 0);
                a10 = __builtin_amdgcn_mfma_i32_16x16x64_i8(ah[1][ks], b0, a10, 0, 0, 0);
                a01 = __builtin_amdgcn_mfma_i32_16x16x64_i8(ah[0][ks], b1, a01, 0, 0, 0);
                a11 = __builtin_amdgcn_mfma_i32_16x16x64_i8(ah[1][ks], b1, a11, 0, 0, 0);
            }
            __builtin_amdgcn_s_setprio(0);
            // integer argmin: maximize accI' (codes ascending -> first-min tie-break)
#pragma unroll
            for (int r = 0; r < 4; ++r) {
                if (a00[r] > best[0][r]) { best[0][r] = a00[r]; bidx[0][r] = code0; }
                if (a01[r] > best[0][r]) { best[0][r] = a01[r]; bidx[0][r] = code1; }
                if (a10[r] > best[1][r]) { best[1][r] = a10[r]; bidx[1][r] = code0; }
                if (a11[r] > best[1][r]) { best[1][r] = a11[r]; bidx[1][r] = code1; }
            }
        }
        // rotate buffers
        const char* tr = rd0; rd0 = rd1; rd1 = rd2; rd2 = tr;
        char* tw = wq0; wq0 = wq1; wq1 = wq2; wq2 = tw;
    }

    // merge across the 16 col-lanes; token = w*32 + m*16 + g*4 + r   (r11-verbatim)
#pragma unroll
    for (int m = 0; m < 2; ++m)
#pragma unroll
        for (int r = 0; r < 4; ++r) {
            int a  = best[m][r];
            int cd = bidx[m][r];
#pragma unroll
            for (int mask = 1; mask <= 8; mask <<= 1) {
                int oa = __shfl_xor(a, mask);
                int oc = __shfl_xor(cd, mask);
                if (oa > a || (oa == a && oc < cd)) { a = oa; cd = oc; }
            }
            if (col == 0) {
                int tl = w * 32 + m * 16 + g * 4 + r;
                winS[tl] = cd;
                // score = cn - 2*dot = cn - (accI' + cnI)*2^-20
                distS[tl] = fmaf((float)(a + cnIS[cd]), -9.5367431640625e-07f, cnS[cd]);
            }
        }
    __syncthreads();

    // tail A: block loss partial = sum over 128 tokens of (xn + score_win)
    if (t < 64) {
        float s = (xnS[t] + distS[t]) + (xnS[t + 64] + distS[t + 64]);
#pragma unroll
        for (int m = 1; m < 64; m <<= 1) s += __shfl_xor(s, m);
        if (t == 0) partials[blockIdx.x] = s;
    }
    // tail B: output = codebook[winner]; wave-uniform row reads, coalesced writes
    const size_t ob = (size_t)blockIdx.x * 8192;  // float4 units
#pragma unroll 4
    for (int i = 0; i < 32; ++i) {
        int f = i * 256 + t;
        int tl = f >> 6, c4 = f & 63;
        float4 qv = ((const float4*)cb)[winS[tl] * 64 + c4];
        ((float4*)out)[ob + f] = qv;
    }
}

// ---------------- kernel 3: deterministic partial reduction (512 partials) ----------------
__global__ __launch_bounds__(256) void reduce_kernel(const float* __restrict__ partials,
                                                     float* __restrict__ out_loss) {
    const int tid = threadIdx.x;
    float s = partials[tid] + partials[tid + 256];
#pragma unroll
    for (int m = 1; m < 64; m <<= 1) s += __shfl_xor(s, m);
    __shared__ float wsum[4];
    if ((tid & 63) == 0) wsum[tid >> 6] = s;
    __syncthreads();
    if (tid == 0) *out_loss = 2.0f * ((wsum[0] + wsum[1]) + (wsum[2] + wsum[3]));
}

extern "C" void kernel_launch(void* const* d_in, const int* in_sizes, int n_in,
                              void* d_out, int out_size, void* d_ws, size_t ws_size,
                              hipStream_t stream) {
    const float* z  = (const float*)d_in[0];   // z_e       [65536,256]
    const float* cb = (const float*)d_in[1];   // codebook  [1024,256]
    float* out = (float*)d_out;
    char*  ws  = (char*)d_ws;

    float*         cn2      = (float*)(ws);                    // 4 KB
    int*           cnI      = (int*)(ws + 4096);               // 4 KB
    float*         partials = (float*)(ws + 8192);             // 2 KB
    unsigned char* cbimg    = (unsigned char*)(ws + 16384);    // 256 KB

    prep_kernel    <<<128, 256, 0, stream>>>(cb, cn2, cnI, cbimg);
    fused_vq_kernel<<<512, 256, 0, stream>>>(z, cbimg, cb, cn2, cnI, out, partials);
    reduce_kernel  <<<1, 256, 0, stream>>>(partials, out + (size_t)N_TOKENS * DIM);
}